// Round 4
// baseline (1437.319 us; speedup 1.0000x reference)
//
#include <hip/hip_runtime.h>
#include <cstdint>
#include <cstddef>

#define D     5120
#define NHEAD 40
#define DH    128
#define LIP   256
#define LK    272          // 256 ip tokens + 16 registers
#define SQ    20480
#define BM    128          // q rows per attention block
#define QTILES (SQ/BM)     // 160

typedef float  f32x4  __attribute__((ext_vector_type(4)));
typedef __bf16 bf16x8 __attribute__((ext_vector_type(8)));
typedef unsigned short u16x8 __attribute__((ext_vector_type(8)));

#if __has_builtin(__builtin_amdgcn_exp2f)
#define EXP2(x) __builtin_amdgcn_exp2f(x)
#else
#define EXP2(x) exp2f(x)
#endif

__device__ __forceinline__ unsigned short f2bf(float f) {
  unsigned u = __builtin_bit_cast(unsigned, f);
  u += 0x7fffu + ((u >> 16) & 1u);      // RNE (inputs finite)
  return (unsigned short)(u >> 16);
}

__device__ __forceinline__ bf16x8 pack8(float a0,float a1,float a2,float a3,
                                        float a4,float a5,float a6,float a7) {
  u16x8 u = { f2bf(a0), f2bf(a1), f2bf(a2), f2bf(a3),
              f2bf(a4), f2bf(a5), f2bf(a6), f2bf(a7) };
  return __builtin_bit_cast(bf16x8, u);
}

// ---------------------------------------------------------------- kernel 1
// concat(ip_x, registers) -> bf16 A [272][5120]
__global__ void prep_A(const float* __restrict__ ipx, const float* __restrict__ regs,
                       unsigned short* __restrict__ A) {
  int idx = blockIdx.x * 256 + threadIdx.x;
  if (idx >= LK * D) return;
  int row = idx / D, col = idx - row * D;
  float v = (row < LIP) ? ipx[(size_t)row * D + col] : regs[(size_t)(row - LIP) * D + col];
  A[idx] = f2bf(v);
}

// ---------------------------------------------------------------- kernel 2
// C[272][5120] = A @ W^T + b for W in {Wk, Wv}. 160 blocks: w = bx/80, 64-col slab.
// bf16 MFMA 16x16x32, BK=64, register-prefetch pipelining, swizzled LDS.
__launch_bounds__(256)
__global__ void proj_gemm(const unsigned short* __restrict__ A,
                          const float* __restrict__ Wk, const float* __restrict__ Wv,
                          const float* __restrict__ bk, const float* __restrict__ bv,
                          float* __restrict__ k_ws, float* __restrict__ v_ws,
                          float* __restrict__ sumsq) {
  __shared__ __align__(16) unsigned short Al[LK * 64];   // [272][64] bf16, 128B rows, swizzled
  __shared__ __align__(16) unsigned short Wl[64 * 64];   // [64][64] bf16, 128B rows, swizzled
  const int bx = blockIdx.x;
  const int w  = bx / 80;                 // 0 = K, 1 = V
  const int n0 = (bx - w * 80) * 64;
  const float* W    = w ? Wv : Wk;
  const float* bias = w ? bv : bk;
  float* outp       = w ? v_ws : k_ws;
  const int tid = threadIdx.x;
  const int lane = tid & 63, wv = tid >> 6, l15 = lane & 15, g = lane >> 4;

  f32x4 acc[17];
#pragma unroll
  for (int f = 0; f < 17; f++) acc[f] = (f32x4){0.f, 0.f, 0.f, 0.f};

  uint4 aR[9]; float4 wR[4];
  // preload chunk 0: A slab (272 rows x 128B = 2176 16B-chunks), W slab (64 rows x 16 float4)
#pragma unroll
  for (int i = 0; i < 9; i++) { int id = tid + i * 256; if (id < 2176) {
      int row = id >> 3, c = id & 7;
      aR[i] = *(const uint4*)((const char*)A + (size_t)row * (D * 2) + c * 16); } }
#pragma unroll
  for (int i = 0; i < 4; i++) { int id = tid + i * 256; int r = id >> 4, c = id & 15;
      wR[i] = *(const float4*)(W + (size_t)(n0 + r) * D + c * 4); }

  for (int kc = 0; kc < 80; ++kc) {
    __syncthreads();
#pragma unroll
    for (int i = 0; i < 9; i++) { int id = tid + i * 256; if (id < 2176) {
        int row = id >> 3, c = id & 7;
        *(uint4*)((char*)Al + row * 128 + ((c * 16) ^ ((row & 7) << 4))) = aR[i]; } }
#pragma unroll
    for (int i = 0; i < 4; i++) { int id = tid + i * 256; int r = id >> 4, c = id & 15;
        unsigned long long pk =
            (unsigned long long)f2bf(wR[i].x)
          | ((unsigned long long)f2bf(wR[i].y) << 16)
          | ((unsigned long long)f2bf(wR[i].z) << 32)
          | ((unsigned long long)f2bf(wR[i].w) << 48);
        *(unsigned long long*)((char*)Wl + r * 128 + ((c * 8) ^ ((r & 7) << 4))) = pk; }
    __syncthreads();
    if (kc < 79) {        // prefetch next chunk into registers; latency hides under MFMA
      int k1 = kc + 1;
#pragma unroll
      for (int i = 0; i < 9; i++) { int id = tid + i * 256; if (id < 2176) {
          int row = id >> 3, c = id & 7;
          aR[i] = *(const uint4*)((const char*)A + (size_t)row * (D * 2) + k1 * 128 + c * 16); } }
#pragma unroll
      for (int i = 0; i < 4; i++) { int id = tid + i * 256; int r = id >> 4, c = id & 15;
          wR[i] = *(const float4*)(W + (size_t)(n0 + r) * D + k1 * 64 + c * 4); }
    }
#pragma unroll
    for (int s = 0; s < 2; s++) {
      int nrow = wv * 16 + l15;
      bf16x8 bfr = *(const bf16x8*)((char*)Wl + nrow * 128 + (((s * 64) + (g * 16)) ^ ((nrow & 7) << 4)));
#pragma unroll
      for (int f = 0; f < 17; f++) {
        int mrow = f * 16 + l15;
        bf16x8 afr = *(const bf16x8*)((char*)Al + mrow * 128 + (((s * 64) + (g * 16)) ^ ((mrow & 7) << 4)));
        acc[f] = __builtin_amdgcn_mfma_f32_16x16x32_bf16(afr, bfr, acc[f], 0, 0, 0);
      }
    }
  }

  const int colg = n0 + wv * 16 + l15;
  const float bsv = bias[colg];
#pragma unroll
  for (int f = 0; f < 17; f++) {
#pragma unroll
    for (int r = 0; r < 4; r++) {
      int m = f * 16 + g * 4 + r;
      float val = acc[f][r] + bsv;
      outp[(size_t)m * D + colg] = val;
      if (w == 0) {
        float x = val * val;
        x += __shfl_xor(x, 1); x += __shfl_xor(x, 2);
        x += __shfl_xor(x, 4); x += __shfl_xor(x, 8);
        if (l15 == 0) atomicAdd(&sumsq[m], x);
      }
    }
  }
}

// ---------------------------------------------------------------- kernel 3
// RMSNorm k -> Kb[40][272][128] bf16 ; v -> VT[40][128][288] bf16 (pad pre-zeroed)
__global__ void norm_cast(const float* __restrict__ k_ws, const float* __restrict__ v_ws,
                          const float* __restrict__ sumsq, const float* __restrict__ nw,
                          unsigned short* __restrict__ Kb, unsigned short* __restrict__ VT) {
  const int row = blockIdx.x;                       // 0..271
  const float rms = rsqrtf(sumsq[row] * (1.0f / D) + 1e-6f);
  for (int col = threadIdx.x; col < D; col += 256) {
    float kv = k_ws[(size_t)row * D + col] * rms * nw[col];
    int head = col >> 7, dim = col & 127;
    Kb[(size_t)head * (LK * DH) + row * DH + dim] = f2bf(kv);
    float vv = v_ws[(size_t)row * D + col];
    VT[(size_t)head * (DH * 288) + dim * 288 + row] = f2bf(vv);
  }
}

// ---------------------------------------------------------------- kernel 4
// attention: one block = (head, 128 q rows); 8 waves x 16 q rows each.
#define PSTR  592                       // P row stride bytes (spreads banks, 16B-aligned)
#define PWAVE (16 * PSTR)               // 9472 B per wave
#define VTOFF (8 * PWAVE)               // 75776 B : P region (overlaps K region)
#define VTSTR 640                       // VT row stride (5x128B -> swizzle stays in-row)
#define SMEM_ATTN (VTOFF + DH * VTSTR)  // 157696 B

__launch_bounds__(512, 2)
__global__ void attn_kern(const float* __restrict__ q,
                          const unsigned short* __restrict__ Kb,
                          const unsigned short* __restrict__ VTb,
                          float* __restrict__ out) {
  extern __shared__ char sm[];
  const int bx = blockIdx.x;
  const int head = bx / QTILES;          // consecutive blocks share a head -> K/VT L2-hot
  const int qt = bx - head * QTILES;
  const int tid = threadIdx.x;
  const int lane = tid & 63, wv = tid >> 6, l15 = lane & 15, g = lane >> 4;

  // issue Q loads early (HBM latency hides under K/VT staging)
  const float* qb = q + (size_t)(qt * BM + wv * 16 + l15) * D + head * DH + g * 8;
  float4 qr[4][2];
#pragma unroll
  for (int s = 0; s < 4; s++) {
    qr[s][0] = *(const float4*)(qb + s * 32);
    qr[s][1] = *(const float4*)(qb + s * 32 + 4);
  }

  // stage K [272][128] (swizzled, offset 0) and VT [128][288->640B rows] (offset VTOFF)
  const uint4* Kg = (const uint4*)(Kb + (size_t)head * LK * DH);
  const uint4* Vg = (const uint4*)(VTb + (size_t)head * DH * 288);
  uint4 kreg[9], vreg[9];
#pragma unroll
  for (int i = 0; i < 9; i++) { int id = tid + i * 512; if (id < 4352) kreg[i] = Kg[id]; }
#pragma unroll
  for (int i = 0; i < 9; i++) { int id = tid + i * 512; vreg[i] = Vg[id]; }
#pragma unroll
  for (int i = 0; i < 9; i++) { int id = tid + i * 512; if (id < 4352) {
      int row = id >> 4, off = (id & 15) << 4;
      *(uint4*)(sm + row * 256 + (off ^ ((row & 7) << 4))) = kreg[i]; } }
#pragma unroll
  for (int i = 0; i < 9; i++) { int id = tid + i * 512;
      int row = id / 36, off = (id - row * 36) << 4;
      *(uint4*)(sm + VTOFF + row * VTSTR + (off ^ ((row & 7) << 4))) = vreg[i]; }

  bf16x8 qf[4];
#pragma unroll
  for (int s = 0; s < 4; s++)
    qf[s] = pack8(qr[s][0].x, qr[s][0].y, qr[s][0].z, qr[s][0].w,
                  qr[s][1].x, qr[s][1].y, qr[s][1].z, qr[s][1].w);

  __syncthreads();

  // S = Q K^T  (acc: row q = 4g+r within wave tile, col key = l15 + 16f)
  f32x4 accs[17];
#pragma unroll
  for (int f = 0; f < 17; f++) accs[f] = (f32x4){0.f, 0.f, 0.f, 0.f};
#pragma unroll
  for (int s = 0; s < 4; s++) {
#pragma unroll
    for (int f = 0; f < 17; f++) {
      int row = f * 16 + l15;
      bf16x8 kf = *(const bf16x8*)(sm + row * 256 + (((s * 64) + (g * 16)) ^ ((row & 7) << 4)));
      accs[f] = __builtin_amdgcn_mfma_f32_16x16x32_bf16(qf[s], kf, accs[f], 0, 0, 0);
    }
  }

  // softmax over 272 keys; reduction = 17 frags in-register + shfl_xor within 16-lane group
  const float CS = 0.12751744f;     // log2(e) / sqrt(128)
  float mx[4] = {-1e30f, -1e30f, -1e30f, -1e30f};
#pragma unroll
  for (int f = 0; f < 17; f++)
#pragma unroll
    for (int r = 0; r < 4; r++) {
      float t = accs[f][r] * CS;
      accs[f][r] = t;
      mx[r] = fmaxf(mx[r], t);
    }
#pragma unroll
  for (int r = 0; r < 4; r++) {
    mx[r] = fmaxf(mx[r], __shfl_xor(mx[r], 1));
    mx[r] = fmaxf(mx[r], __shfl_xor(mx[r], 2));
    mx[r] = fmaxf(mx[r], __shfl_xor(mx[r], 4));
    mx[r] = fmaxf(mx[r], __shfl_xor(mx[r], 8));
  }
  float sum[4] = {0.f, 0.f, 0.f, 0.f};
#pragma unroll
  for (int f = 0; f < 17; f++)
#pragma unroll
    for (int r = 0; r < 4; r++) {
      float p = EXP2(accs[f][r] - mx[r]);
      accs[f][r] = p;
      sum[r] += p;
    }
#pragma unroll
  for (int r = 0; r < 4; r++) {
    sum[r] += __shfl_xor(sum[r], 1);
    sum[r] += __shfl_xor(sum[r], 2);
    sum[r] += __shfl_xor(sum[r], 4);
    sum[r] += __shfl_xor(sum[r], 8);
  }

  __syncthreads();                 // all waves done reading K region; safe to overwrite with P

  // write P (bf16) into per-wave LDS tile [16 q][296 keys, 592B stride]; zero pad keys 272..287
  char* pb = sm + wv * PWAVE;
#pragma unroll
  for (int f = 0; f < 17; f++)
#pragma unroll
    for (int r = 0; r < 4; r++)
      *(unsigned short*)(pb + (g * 4 + r) * PSTR + (l15 + f * 16) * 2) = f2bf(accs[f][r]);
  if (lane < 32)
    *(uint4*)(pb + (lane >> 1) * PSTR + 544 + (lane & 1) * 16) = (uint4){0, 0, 0, 0};

  // O = P V  (9 K-steps of 32 keys; VT pad cols are zeros, P pad zeros)
  f32x4 acco[8];
#pragma unroll
  for (int f = 0; f < 8; f++) acco[f] = (f32x4){0.f, 0.f, 0.f, 0.f};
#pragma unroll
  for (int c = 0; c < 9; c++) {
    bf16x8 pa = *(const bf16x8*)(pb + l15 * PSTR + c * 64 + g * 16);
#pragma unroll
    for (int f = 0; f < 8; f++) {
      int dim = f * 16 + l15;
      bf16x8 vb = *(const bf16x8*)(sm + VTOFF + dim * VTSTR + (((c * 64) + (g * 16)) ^ ((dim & 7) << 4)));
      acco[f] = __builtin_amdgcn_mfma_f32_16x16x32_bf16(pa, vb, acco[f], 0, 0, 0);
    }
  }

  float inv[4];
#pragma unroll
  for (int r = 0; r < 4; r++) inv[r] = 1.0f / sum[r];
  float* ob = out + (size_t)(qt * BM + wv * 16) * D + head * DH;
#pragma unroll
  for (int f = 0; f < 8; f++)
#pragma unroll
    for (int r = 0; r < 4; r++)
      ob[(size_t)(g * 4 + r) * D + f * 16 + l15] = acco[f][r] * inv[r];
}

// ---------------------------------------------------------------- launch
extern "C" void kernel_launch(void* const* d_in, const int* in_sizes, int n_in,
                              void* d_out, int out_size, void* d_ws, size_t ws_size,
                              hipStream_t stream) {
  const float* q   = (const float*)d_in[0];
  const float* ipx = (const float*)d_in[1];
  const float* rgs = (const float*)d_in[2];
  const float* Wk  = (const float*)d_in[3];
  const float* bk  = (const float*)d_in[4];
  const float* Wv  = (const float*)d_in[5];
  const float* bv  = (const float*)d_in[6];
  const float* nw  = (const float*)d_in[7];

  char* ws = (char*)d_ws;
  // ws layout (bytes):
  constexpr size_t OFF_A  = 0;                    // A bf16   [272][5120]      2,785,280
  constexpr size_t OFF_KW = 2785280;              // k fp32   [272][5120]      5,570,560
  constexpr size_t OFF_VW = 8355840;              // v fp32   [272][5120]      5,570,560
  constexpr size_t OFF_KB = 13926400;             // K bf16   [40][272][128]   2,785,280
  constexpr size_t OFF_VT = 16711680;             // VT bf16  [40][128][288]   2,949,120
  constexpr size_t OFF_SS = 19660800;             // sumsq fp32 [272]          1,088
  unsigned short* A    = (unsigned short*)(ws + OFF_A);
  float* k_ws          = (float*)(ws + OFF_KW);
  float* v_ws          = (float*)(ws + OFF_VW);
  unsigned short* Kb   = (unsigned short*)(ws + OFF_KB);
  unsigned short* VT   = (unsigned short*)(ws + OFF_VT);
  float* sumsq         = (float*)(ws + OFF_SS);

  hipMemsetAsync(sumsq, 0, 272 * 4, stream);
  hipMemsetAsync(VT, 0, (size_t)NHEAD * DH * 288 * 2, stream);   // zero incl. key-pad 272..287

  prep_A<<<(LK * D + 255) / 256, 256, 0, stream>>>(ipx, rgs, A);
  proj_gemm<<<160, 256, 0, stream>>>(A, Wk, Wv, bk, bv, k_ws, v_ws, sumsq);
  norm_cast<<<LK, 256, 0, stream>>>(k_ws, v_ws, sumsq, nw, Kb, VT);

  hipFuncSetAttribute((const void*)attn_kern,
                      hipFuncAttributeMaxDynamicSharedMemorySize, SMEM_ATTN);
  attn_kern<<<NHEAD * QTILES, 512, SMEM_ATTN, stream>>>(q, Kb, VT, (float*)d_out);
}